// Round 11
// baseline (234.490 us; speedup 1.0000x reference)
//
#include <hip/hip_runtime.h>
#include <stdint.h>

#define D_FEAT 64
#define NEG_INF_BITS 0xFF800000u
#define ENC_NEG_INF  0x007FFFFFu   // order-preserving encoding of -inf
#define SENTINEL     0xFFFFFFFFu   // padded empty slot in packed (skipped, never loaded)
#define NPB 64                      // nodes per bucket (= 1 << BSHIFT)
#define BSHIFT 6
#define BM_BLOCK 256                // bucket_max threads (4 waves) — proven config
#define MAXB 2048                   // max buckets (N <= 131072)
#define PAD 16                      // reservation granularity = 64B line (16 slots)
#define PL_BLOCKS_PAD 64            // padded path: run/bucket ~25 edges -> 1-2 lines, block-exclusive
#define PL_BLOCKS_STD 256           // fallback path (R10 proven)
#define PL_THREADS 1024
#define O_CAP 65536                 // overflow side-list entries (never hit on sane data)

// Order-preserving float->uint: enc monotone increasing with float value.
__device__ __forceinline__ unsigned enc_f32(float v) {
    unsigned b = __float_as_uint(v);
    return ((int)b >= 0) ? (b ^ 0x80000000u) : ~b;
}
__device__ __forceinline__ unsigned dec_bits(unsigned u) {
    // decoded float bits; ENC_NEG_INF maps to 0.0f
    if (u == ENC_NEG_INF) return 0u;
    return (u & 0x80000000u) ? (u ^ 0x80000000u) : ~u;
}

// ---------- D2: place into fixed-stride buckets.
// pad>0: reservations rounded up to pad slots (64B) => each packed line written by ONE
// block only (no cross-XCD line bouncing); gap slots filled with SENTINEL.
// Intra-bucket order nondeterministic; max is order-independent -> bit-exact.
__global__ void __launch_bounds__(PL_THREADS)
place_kernel(const int* __restrict__ src, const int* __restrict__ dst,
             int* __restrict__ cnt, int* __restrict__ ovf_cnt,
             int* __restrict__ ovf_dst, int* __restrict__ ovf_src,
             unsigned* __restrict__ packed,
             int E, int Te, int B, int cap, int aligned4, int pad) {
    __shared__ int lcnt[MAXB];                   // per-bucket count (this chunk)
    __shared__ int lcur[MAXB];                   // reservation base, then cursor
    int t = blockIdx.x;
    int beg = t * Te;
    int end = min(E, beg + Te);
    if (beg >= end) return;                      // block-uniform, before any sync
    for (int i = threadIdx.x; i < B; i += blockDim.x) lcnt[i] = 0;
    __syncthreads();
    int nE = end - beg;
    int n4 = aligned4 ? (nE >> 2) : 0;           // beg is a multiple of 4
    const int4* d4 = (const int4*)(dst + beg);
    // pass 1: count this chunk
    for (int k = threadIdx.x; k < n4; k += blockDim.x) {
        int4 d = d4[k];
        atomicAdd(&lcnt[d.x >> BSHIFT], 1);
        atomicAdd(&lcnt[d.y >> BSHIFT], 1);
        atomicAdd(&lcnt[d.z >> BSHIFT], 1);
        atomicAdd(&lcnt[d.w >> BSHIFT], 1);
    }
    for (int i = beg + (n4 << 2) + threadIdx.x; i < end; i += blockDim.x)
        atomicAdd(&lcnt[dst[i] >> BSHIFT], 1);
    __syncthreads();
    // reserve per-bucket ranges, padded to line granularity when pad>0
    for (int i = threadIdx.x; i < B; i += blockDim.x) {
        int c = lcnt[i];
        int res = (pad > 1) ? ((c + pad - 1) & ~(pad - 1)) : c;
        lcur[i] = c ? atomicAdd(&cnt[i], res) : 0;
    }
    __syncthreads();
    // pass 2: place (chunk is L2-hot from pass 1)
    for (int i = beg + threadIdx.x; i < end; i += blockDim.x) {
        int d = dst[i];
        int s = src[i];
        int b = d >> BSHIFT;
        int pos = atomicAdd(&lcur[b], 1);        // bucket-global slot
        if (pos < cap) {
            packed[(size_t)b * cap + pos] = (unsigned)s | ((unsigned)(d & (NPB - 1)) << 17);
        } else {
            int o = atomicAdd(ovf_cnt, 1);
            if (o < O_CAP) { ovf_dst[o] = d; ovf_src[o] = s; }
        }
    }
    if (pad > 1) {
        __syncthreads();
        // fill this block's padding gap [base+c, base+padded) with SENTINEL (clamped to cap)
        for (int i = threadIdx.x; i < B; i += blockDim.x) {
            int c = lcnt[i];
            if (c) {
                int curv = lcur[i];                               // base + c
                int base = curv - c;
                int endp = base + ((c + pad - 1) & ~(pad - 1));   // base + padded
                int fe = min(endp, cap);
                for (int s2 = curv; s2 < fe; ++s2)
                    packed[(size_t)i * cap + s2] = SENTINEL;
            }
        }
    }
}

// ---------- D3: per-bucket scatter-max in LDS (proven body: lane=feature, 0 conflicts) ----------
__global__ void __launch_bounds__(BM_BLOCK)
bucket_max_kernel(const float* __restrict__ h,
                  const int* __restrict__ cnt, const int* __restrict__ ovf_cnt,
                  const int* __restrict__ ovf_dst, const int* __restrict__ ovf_src,
                  const int* __restrict__ src, const int* __restrict__ dst,
                  const unsigned* __restrict__ packed,
                  float* __restrict__ out, int N, int E, int cap) {
    __shared__ unsigned buf[NPB * D_FEAT];   // 16 KB
    int b = blockIdx.x;
    int tid = threadIdx.x;
    int node0 = b << BSHIFT;
    int nvals = (min(NPB, N - node0)) * D_FEAT;

    for (int i = tid; i < NPB * D_FEAT; i += BM_BLOCK) buf[i] = ENC_NEG_INF;
    __syncthreads();

    int total = cnt[b];
    int beg = b * cap;
    int end = beg + min(total, cap);
    int wid = tid >> 6;
    int lane = tid & 63;

    for (int base = beg + (wid << 6); base < end; base += BM_BLOCK) {
        int nk = min(64, end - base);
        unsigned p = (lane < nk) ? packed[base + lane] : SENTINEL;
        int j = 0;
        for (; j + 8 <= nk; j += 8) {
            unsigned q[8];
            #pragma unroll
            for (int k = 0; k < 8; ++k) q[k] = (unsigned)__shfl((int)p, j + k);
            #pragma unroll
            for (int k = 0; k < 8; ++k) {
                if (q[k] != SENTINEL) {                 // wave-uniform branch (broadcast q)
                    float v = h[(size_t)(q[k] & 0x1FFFFu) * D_FEAT + lane];
                    atomicMax(&buf[(q[k] >> 17) * D_FEAT + lane], enc_f32(v));
                }
            }
        }
        for (; j < nk; ++j) {
            unsigned pj = (unsigned)__shfl((int)p, j);
            if (pj != SENTINEL) {
                float v = h[(size_t)(pj & 0x1FFFFu) * D_FEAT + lane];
                atomicMax(&buf[(pj >> 17) * D_FEAT + lane], enc_f32(v));
            }
        }
    }

    // ---- overflow safety net (ov == 0 on sane data: one broadcast load + branch) ----
    int ov = *ovf_cnt;
    if (ov > 0) {
        if (ov <= O_CAP) {
            for (int i = 0; i < ov; ++i) {           // list entries broadcast to all lanes
                int d = ovf_dst[i];
                if ((d >> BSHIFT) == b) {
                    float v = h[(size_t)ovf_src[i] * D_FEAT + lane];
                    atomicMax(&buf[(d & (NPB - 1)) * D_FEAT + lane], enc_f32(v));
                }
            }
        } else if (total > cap) {
            // truncated list: rescan all edges for this bucket (max is idempotent)
            for (int e = tid; e < E; e += BM_BLOCK) {
                int d = dst[e];
                if ((d >> BSHIFT) == b) {
                    const float* hr = h + (size_t)src[e] * D_FEAT;
                    int row = (d & (NPB - 1)) * D_FEAT;
                    for (int f = 0; f < D_FEAT; ++f)
                        atomicMax(&buf[row + f], enc_f32(hr[f]));
                }
            }
        }
    }
    __syncthreads();

    if (nvals == NPB * D_FEAT) {
        uint4* o4 = (uint4*)(out + (size_t)node0 * D_FEAT);
        const uint4* b4 = (const uint4*)buf;
        for (int i = tid; i < (NPB * D_FEAT) / 4; i += BM_BLOCK) {
            uint4 u = b4[i];
            uint4 r;
            r.x = dec_bits(u.x); r.y = dec_bits(u.y);
            r.z = dec_bits(u.z); r.w = dec_bits(u.w);
            o4[i] = r;
        }
    } else {
        unsigned* o = (unsigned*)(out + (size_t)node0 * D_FEAT);
        for (int i = tid; i < nvals; i += BM_BLOCK) o[i] = dec_bits(buf[i]);
    }
}

// ---------- fallback: atomic scatter (large-N / tiny-ws path) ----------
__global__ void init_out_kernel(uint4* __restrict__ out, int n4) {
    int i = blockIdx.x * blockDim.x + threadIdx.x;
    if (i < n4) {
        uint4 v;
        v.x = NEG_INF_BITS; v.y = NEG_INF_BITS; v.z = NEG_INF_BITS; v.w = NEG_INF_BITS;
        out[i] = v;
    }
}
__global__ void scatter_max_kernel(const float* __restrict__ h, const int* __restrict__ src,
                                   const int* __restrict__ dst, float* __restrict__ out, int E) {
    int gid = blockIdx.x * blockDim.x + threadIdx.x;
    int e = gid >> 6;
    if (e >= E) return;
    int lane = gid & 63;
    float v = h[src[e] * D_FEAT + lane];
    int* addr = (int*)(out + dst[e] * D_FEAT + lane);
    if (v >= 0.0f) atomicMax(addr, __float_as_int(v));
    else           atomicMin((unsigned int*)addr, __float_as_uint(v));
}
__global__ void finalize_kernel(float* __restrict__ out, int n) {
    int i = blockIdx.x * blockDim.x + threadIdx.x;
    if (i < n && __float_as_uint(out[i]) == NEG_INF_BITS) out[i] = 0.0f;
}

// ---------- launch ----------
extern "C" void kernel_launch(void* const* d_in, const int* in_sizes, int n_in,
                              void* d_out, int out_size, void* d_ws, size_t ws_size,
                              hipStream_t stream) {
    const float* h = (const float*)d_in[0];
    const int* edge_index = (const int*)d_in[1];
    int E = in_sizes[1] / 2;                 // edge_index is [2, E] row-major
    const int* src = edge_index;
    const int* dst = edge_index + E;
    float* out = (float*)d_out;
    int N = out_size / D_FEAT;

    int B = (N + NPB - 1) >> BSHIFT;

    if (N <= (1 << 17) && B <= MAXB && E > 0) {
        int meanb = E / B;
        // padded path: expected padded total = meanb + PL_BLOCKS_PAD * ~avg_waste(8); x1.25 margin
        int capP = (((meanb + PL_BLOCKS_PAD * 10) * 5) / 4 + 63) & ~63;
        if (capP < 128) capP = 128;
        size_t needP = ((size_t)B + 1 + 2 * (size_t)O_CAP + (size_t)B * capP) * sizeof(int);
        // unpadded fallback (R10-proven): cap = 1.25x mean degree
        int cap0 = ((meanb * 5) / 4 + 63) & ~63;
        if (cap0 < 128) cap0 = 128;
        size_t need0 = ((size_t)B + 1 + 2 * (size_t)O_CAP + (size_t)B * cap0) * sizeof(int);

        int use_pad = (ws_size >= needP) ? 1 : 0;
        int cap = use_pad ? capP : cap0;
        size_t need = use_pad ? needP : need0;

        if (ws_size >= need) {
            int* cnt         = (int*)d_ws;                   // [B]
            int* ovf_cnt     = cnt + B;                      // [1]
            int* ovf_dst     = ovf_cnt + 1;                  // [O_CAP]
            int* ovf_src     = ovf_dst + O_CAP;              // [O_CAP]
            unsigned* packed = (unsigned*)(ovf_src + O_CAP); // [B*cap]

            int aligned4 = (((((uintptr_t)dst) | ((uintptr_t)src)) & 15) == 0) ? 1 : 0;

            hipMemsetAsync(cnt, 0, (size_t)(B + 1) * sizeof(int), stream);

            int pl_blocks = use_pad ? PL_BLOCKS_PAD : PL_BLOCKS_STD;
            int pad       = use_pad ? PAD : 1;
            int Te = ((E + pl_blocks - 1) / pl_blocks + 3) & ~3;   // chunk, multiple of 4
            place_kernel<<<pl_blocks, PL_THREADS, 0, stream>>>(
                src, dst, cnt, ovf_cnt, ovf_dst, ovf_src, packed, E, Te, B, cap, aligned4, pad);

            bucket_max_kernel<<<B, BM_BLOCK, 0, stream>>>(
                h, cnt, ovf_cnt, ovf_dst, ovf_src, src, dst, packed, out, N, E, cap);
            return;
        }
    }
    // fallback
    int n4 = out_size / 4;
    init_out_kernel<<<(n4 + 255) / 256, 256, 0, stream>>>((uint4*)out, n4);
    long long total = (long long)E * 64;
    scatter_max_kernel<<<(int)((total + 255) / 256), 256, 0, stream>>>(h, src, dst, out, E);
    finalize_kernel<<<(out_size + 255) / 256, 256, 0, stream>>>(out, out_size);
}

// Round 12
// 176.278 us; speedup vs baseline: 1.3302x; 1.3302x over previous
//
#include <hip/hip_runtime.h>
#include <stdint.h>

#define D_FEAT 64
#define NEG_INF_BITS 0xFF800000u
#define ENC_NEG_INF  0x007FFFFFu   // order-preserving encoding of -inf
#define NPB 64                      // nodes per bucket (= 1 << BSHIFT)
#define BSHIFT 6
#define BM_BLOCK 256                // bucket_max threads (4 waves) — proven config
#define MAXB 2048                   // max buckets (N <= 131072)
#define CH 4096                     // place: edges per chunk (multiple of 4)
#define PL_THREADS 512
#define O_CAP 65536                 // overflow side-list entries (never hit on sane data)

// Order-preserving float->uint: enc monotone increasing with float value.
__device__ __forceinline__ unsigned enc_f32(float v) {
    unsigned b = __float_as_uint(v);
    return ((int)b >= 0) ? (b ^ 0x80000000u) : ~b;
}
__device__ __forceinline__ unsigned dec_bits(unsigned u) {
    // decoded float bits; ENC_NEG_INF maps to 0.0f
    if (u == ENC_NEG_INF) return 0u;
    return (u & 0x80000000u) ? (u ^ 0x80000000u) : ~u;
}

// ---------- D2: place via in-LDS counting sort -> COALESCED packed stores ----------
// Per chunk: LDS count -> block scan (local offsets) -> one reservation atomic per
// non-empty bucket -> stage edges bucket-sorted in LDS -> linear sweep writes runs
// contiguously (wave stores merge into full lines).
// Intra-bucket order nondeterministic across blocks; max is order-independent -> bit-exact.
__global__ void __launch_bounds__(PL_THREADS)
place_kernel(const int* __restrict__ src, const int* __restrict__ dst,
             int* __restrict__ cnt, int* __restrict__ ovf_cnt,
             int* __restrict__ ovf_dst, int* __restrict__ ovf_src,
             unsigned* __restrict__ packed,
             int E, int B, int cap, int aligned4) {
    __shared__ int lh[MAXB];        // per-bucket count, then rank cursor
    __shared__ int lo[MAXB];        // local exclusive offsets (intact through staging)
    __shared__ int gb[MAXB];        // b*cap + global_reservation - lo[b]
    __shared__ unsigned sval[CH];   // bucket-sorted packed values
    __shared__ int sdel[CH];        // per-slot delta (gpos = sdel[r] + r); also scan scratch
    const int tid = threadIdx.x;
    const int t = blockIdx.x;
    int beg = t * CH;
    int end = min(E, beg + CH);
    if (beg >= end) return;                      // block-uniform, before any sync
    int nE = end - beg;

    // ---- phase 1: count ----
    for (int i = tid; i < B; i += PL_THREADS) lh[i] = 0;
    __syncthreads();
    int n4 = aligned4 ? (nE >> 2) : 0;           // beg is a multiple of 4
    const int4* d4 = (const int4*)(dst + beg);
    for (int k = tid; k < n4; k += PL_THREADS) {
        int4 d = d4[k];
        atomicAdd(&lh[d.x >> BSHIFT], 1);
        atomicAdd(&lh[d.y >> BSHIFT], 1);
        atomicAdd(&lh[d.z >> BSHIFT], 1);
        atomicAdd(&lh[d.w >> BSHIFT], 1);
    }
    for (int i = beg + (n4 << 2) + tid; i < end; i += PL_THREADS)
        atomicAdd(&lh[dst[i] >> BSHIFT], 1);
    __syncthreads();

    // ---- phase 2: block scan over buckets (thread owns 4 consecutive) + reservations ----
    int i0 = tid << 2;
    int c0 = 0, c1 = 0, c2 = 0, c3 = 0;
    if (i0 + 0 < B) c0 = lh[i0 + 0];
    if (i0 + 1 < B) c1 = lh[i0 + 1];
    if (i0 + 2 < B) c2 = lh[i0 + 2];
    if (i0 + 3 < B) c3 = lh[i0 + 3];
    int s = c0 + c1 + c2 + c3;
    int* scr = sdel;                              // scan scratch (freed before staging)
    scr[tid] = s;
    __syncthreads();
    for (int off = 1; off < PL_THREADS; off <<= 1) {
        int v = (tid >= off) ? scr[tid - off] : 0;
        __syncthreads();
        scr[tid] += v;
        __syncthreads();
    }
    int excl = scr[tid] - s;
    // lo + global reservation (one atomic per non-empty bucket)
    {
        int e0 = excl;
        if (i0 + 0 < B) { lo[i0+0] = e0; if (c0) gb[i0+0] = (i0+0)*cap + atomicAdd(&cnt[i0+0], c0) - e0; }
        e0 += c0;
        if (i0 + 1 < B) { lo[i0+1] = e0; if (c1) gb[i0+1] = (i0+1)*cap + atomicAdd(&cnt[i0+1], c1) - e0; }
        e0 += c1;
        if (i0 + 2 < B) { lo[i0+2] = e0; if (c2) gb[i0+2] = (i0+2)*cap + atomicAdd(&cnt[i0+2], c2) - e0; }
        e0 += c2;
        if (i0 + 3 < B) { lo[i0+3] = e0; if (c3) gb[i0+3] = (i0+3)*cap + atomicAdd(&cnt[i0+3], c3) - e0; }
    }
    __syncthreads();

    // ---- phase 3: re-zero rank cursors ----
    for (int i = tid; i < B; i += PL_THREADS) lh[i] = 0;
    __syncthreads();

    // ---- phase 4: stage bucket-sorted into LDS ----
    for (int i = beg + tid; i < end; i += PL_THREADS) {
        int d = dst[i];
        int sv = src[i];
        int b = d >> BSHIFT;
        unsigned val = (unsigned)sv | ((unsigned)(d & (NPB - 1)) << 17);
        int rank = atomicAdd(&lh[b], 1);
        int r = lo[b] + rank;
        sval[r] = val;
        // global slot within bucket = gb[b] + r - b*cap; overflow if >= cap
        int gslot = gb[b] + r - b * cap;
        if (gslot < cap) {
            sdel[r] = gb[b];
        } else {
            sdel[r] = INT32_MIN;                 // writer skips
            int o = atomicAdd(ovf_cnt, 1);
            if (o < O_CAP) { ovf_dst[o] = d; ovf_src[o] = sv; }
        }
    }
    __syncthreads();

    // ---- phase 5: coalesced write-out (runs are contiguous in both r and gpos) ----
    for (int r = tid; r < nE; r += PL_THREADS) {
        int del = sdel[r];
        if (del != INT32_MIN) packed[(size_t)(del + r)] = sval[r];
    }
}

// ---------- D3: per-bucket scatter-max in LDS (R10-proven body: lane=feature, 0 conflicts) ----------
__global__ void __launch_bounds__(BM_BLOCK)
bucket_max_kernel(const float* __restrict__ h,
                  const int* __restrict__ cnt, const int* __restrict__ ovf_cnt,
                  const int* __restrict__ ovf_dst, const int* __restrict__ ovf_src,
                  const int* __restrict__ src, const int* __restrict__ dst,
                  const unsigned* __restrict__ packed,
                  float* __restrict__ out, int N, int E, int cap) {
    __shared__ unsigned buf[NPB * D_FEAT];   // 16 KB
    int b = blockIdx.x;
    int tid = threadIdx.x;
    int node0 = b << BSHIFT;
    int nvals = (min(NPB, N - node0)) * D_FEAT;

    for (int i = tid; i < NPB * D_FEAT; i += BM_BLOCK) buf[i] = ENC_NEG_INF;
    __syncthreads();

    int total = cnt[b];
    int beg = b * cap;
    int end = beg + min(total, cap);
    int wid = tid >> 6;
    int lane = tid & 63;

    for (int base = beg + (wid << 6); base < end; base += BM_BLOCK) {
        int nk = min(64, end - base);
        unsigned p = (lane < nk) ? packed[base + lane] : 0u;
        int j = 0;
        for (; j + 8 <= nk; j += 8) {
            unsigned q[8];
            float v[8];
            #pragma unroll
            for (int k = 0; k < 8; ++k) q[k] = (unsigned)__shfl((int)p, j + k);
            #pragma unroll
            for (int k = 0; k < 8; ++k) v[k] = h[(size_t)(q[k] & 0x1FFFFu) * D_FEAT + lane];
            #pragma unroll
            for (int k = 0; k < 8; ++k)
                atomicMax(&buf[(q[k] >> 17) * D_FEAT + lane], enc_f32(v[k]));
        }
        for (; j < nk; ++j) {
            unsigned pj = (unsigned)__shfl((int)p, j);
            float v = h[(size_t)(pj & 0x1FFFFu) * D_FEAT + lane];
            atomicMax(&buf[(pj >> 17) * D_FEAT + lane], enc_f32(v));
        }
    }

    // ---- overflow safety net (ov == 0 on sane data: one broadcast load + branch) ----
    int ov = *ovf_cnt;
    if (ov > 0) {
        if (ov <= O_CAP) {
            for (int i = 0; i < ov; ++i) {           // list entries broadcast to all lanes
                int d = ovf_dst[i];
                if ((d >> BSHIFT) == b) {
                    float v = h[(size_t)ovf_src[i] * D_FEAT + lane];
                    atomicMax(&buf[(d & (NPB - 1)) * D_FEAT + lane], enc_f32(v));
                }
            }
        } else if (total > cap) {
            // truncated list: rescan all edges for this bucket (max is idempotent)
            for (int e = tid; e < E; e += BM_BLOCK) {
                int d = dst[e];
                if ((d >> BSHIFT) == b) {
                    const float* hr = h + (size_t)src[e] * D_FEAT;
                    int row = (d & (NPB - 1)) * D_FEAT;
                    for (int f = 0; f < D_FEAT; ++f)
                        atomicMax(&buf[row + f], enc_f32(hr[f]));
                }
            }
        }
    }
    __syncthreads();

    if (nvals == NPB * D_FEAT) {
        uint4* o4 = (uint4*)(out + (size_t)node0 * D_FEAT);
        const uint4* b4 = (const uint4*)buf;
        for (int i = tid; i < (NPB * D_FEAT) / 4; i += BM_BLOCK) {
            uint4 u = b4[i];
            uint4 r;
            r.x = dec_bits(u.x); r.y = dec_bits(u.y);
            r.z = dec_bits(u.z); r.w = dec_bits(u.w);
            o4[i] = r;
        }
    } else {
        unsigned* o = (unsigned*)(out + (size_t)node0 * D_FEAT);
        for (int i = tid; i < nvals; i += BM_BLOCK) o[i] = dec_bits(buf[i]);
    }
}

// ---------- fallback: atomic scatter (large-N / tiny-ws path) ----------
__global__ void init_out_kernel(uint4* __restrict__ out, int n4) {
    int i = blockIdx.x * blockDim.x + threadIdx.x;
    if (i < n4) {
        uint4 v;
        v.x = NEG_INF_BITS; v.y = NEG_INF_BITS; v.z = NEG_INF_BITS; v.w = NEG_INF_BITS;
        out[i] = v;
    }
}
__global__ void scatter_max_kernel(const float* __restrict__ h, const int* __restrict__ src,
                                   const int* __restrict__ dst, float* __restrict__ out, int E) {
    int gid = blockIdx.x * blockDim.x + threadIdx.x;
    int e = gid >> 6;
    if (e >= E) return;
    int lane = gid & 63;
    float v = h[src[e] * D_FEAT + lane];
    int* addr = (int*)(out + dst[e] * D_FEAT + lane);
    if (v >= 0.0f) atomicMax(addr, __float_as_int(v));
    else           atomicMin((unsigned int*)addr, __float_as_uint(v));
}
__global__ void finalize_kernel(float* __restrict__ out, int n) {
    int i = blockIdx.x * blockDim.x + threadIdx.x;
    if (i < n && __float_as_uint(out[i]) == NEG_INF_BITS) out[i] = 0.0f;
}

// ---------- launch ----------
extern "C" void kernel_launch(void* const* d_in, const int* in_sizes, int n_in,
                              void* d_out, int out_size, void* d_ws, size_t ws_size,
                              hipStream_t stream) {
    const float* h = (const float*)d_in[0];
    const int* edge_index = (const int*)d_in[1];
    int E = in_sizes[1] / 2;                 // edge_index is [2, E] row-major
    const int* src = edge_index;
    const int* dst = edge_index + E;
    float* out = (float*)d_out;
    int N = out_size / D_FEAT;

    int B = (N + NPB - 1) >> BSHIFT;

    // fixed per-bucket capacity: 1.25x mean degree, 64-aligned, floor 128
    int cap = 0;
    if (B > 0) {
        cap = (((E / B) * 5) / 4 + 63) & ~63;
        if (cap < 128) cap = 128;
    }
    size_t need = ((size_t)B + 1 + 2 * (size_t)O_CAP + (size_t)B * cap) * sizeof(int);

    if (N <= (1 << 17) && B <= MAXB && E > 0 && cap > 0 && ws_size >= need) {
        int* cnt         = (int*)d_ws;                   // [B]
        int* ovf_cnt     = cnt + B;                      // [1]
        int* ovf_dst     = ovf_cnt + 1;                  // [O_CAP]
        int* ovf_src     = ovf_dst + O_CAP;              // [O_CAP]
        unsigned* packed = (unsigned*)(ovf_src + O_CAP); // [B*cap]

        int aligned4 = (((((uintptr_t)dst) | ((uintptr_t)src)) & 15) == 0) ? 1 : 0;

        hipMemsetAsync(cnt, 0, (size_t)(B + 1) * sizeof(int), stream);

        int pl_blocks = (E + CH - 1) / CH;
        place_kernel<<<pl_blocks, PL_THREADS, 0, stream>>>(
            src, dst, cnt, ovf_cnt, ovf_dst, ovf_src, packed, E, B, cap, aligned4);

        bucket_max_kernel<<<B, BM_BLOCK, 0, stream>>>(
            h, cnt, ovf_cnt, ovf_dst, ovf_src, src, dst, packed, out, N, E, cap);
    } else {
        int n4 = out_size / 4;
        init_out_kernel<<<(n4 + 255) / 256, 256, 0, stream>>>((uint4*)out, n4);
        long long total = (long long)E * 64;
        scatter_max_kernel<<<(int)((total + 255) / 256), 256, 0, stream>>>(h, src, dst, out, E);
        finalize_kernel<<<(out_size + 255) / 256, 256, 0, stream>>>(out, out_size);
    }
}

// Round 13
// 155.802 us; speedup vs baseline: 1.5050x; 1.1314x over previous
//
#include <hip/hip_runtime.h>
#include <stdint.h>

#define D_FEAT 64
#define NEG_INF_BITS 0xFF800000u
#define ENC_NEG_INF  0x007FFFFFu   // order-preserving encoding of -inf
#define NPB 64                      // nodes per bucket (= 1 << BSHIFT)
#define BSHIFT 6
#define BM_BLOCK 256                // bucket_max threads (4 waves) — proven config
#define MAXB 2048                   // max buckets (N <= 131072)
#define PL_BLOCKS 256               // place: 1 block/CU
#define PL_THREADS 1024             // 16 waves/CU
#define O_CAP 65536                 // overflow side-list entries (never hit on sane data)

// Order-preserving float->uint: enc monotone increasing with float value.
__device__ __forceinline__ unsigned enc_f32(float v) {
    unsigned b = __float_as_uint(v);
    return ((int)b >= 0) ? (b ^ 0x80000000u) : ~b;
}
__device__ __forceinline__ unsigned dec_bits(unsigned u) {
    // decoded float bits; ENC_NEG_INF maps to 0.0f
    if (u == ENC_NEG_INF) return 0u;
    return (u & 0x80000000u) ? (u ^ 0x80000000u) : ~u;
}

// ---------- D2: place into fixed-stride buckets (LDS count -> one reservation atomic
// per (block,bucket) -> LDS cursors). No hist/scan dispatches needed.
// Intra-bucket order nondeterministic; max is order-independent -> bit-exact.
__global__ void __launch_bounds__(PL_THREADS)
place_kernel(const int* __restrict__ src, const int* __restrict__ dst,
             int* __restrict__ cnt, int* __restrict__ ovf_cnt,
             int* __restrict__ ovf_dst, int* __restrict__ ovf_src,
             unsigned* __restrict__ packed,
             int E, int Te, int B, int cap, int aligned4) {
    __shared__ int lh[MAXB];
    int t = blockIdx.x;
    int beg = t * Te;
    int end = min(E, beg + Te);
    if (beg >= end) return;                      // block-uniform, before any sync
    for (int i = threadIdx.x; i < B; i += blockDim.x) lh[i] = 0;
    __syncthreads();
    int nE = end - beg;
    int n4 = aligned4 ? (nE >> 2) : 0;           // beg is a multiple of 4
    const int4* d4 = (const int4*)(dst + beg);
    // pass 1: count this chunk
    for (int k = threadIdx.x; k < n4; k += blockDim.x) {
        int4 d = d4[k];
        atomicAdd(&lh[d.x >> BSHIFT], 1);
        atomicAdd(&lh[d.y >> BSHIFT], 1);
        atomicAdd(&lh[d.z >> BSHIFT], 1);
        atomicAdd(&lh[d.w >> BSHIFT], 1);
    }
    for (int i = beg + (n4 << 2) + threadIdx.x; i < end; i += blockDim.x)
        atomicAdd(&lh[dst[i] >> BSHIFT], 1);
    __syncthreads();
    // reserve contiguous per-bucket slot ranges (global slot index within bucket)
    for (int i = threadIdx.x; i < B; i += blockDim.x) {
        int c = lh[i];
        lh[i] = c ? atomicAdd(&cnt[i], c) : 0;
    }
    __syncthreads();
    // pass 2: place (chunk is L2-hot from pass 1)
    for (int i = beg + threadIdx.x; i < end; i += blockDim.x) {
        int d = dst[i];
        int s = src[i];
        int b = d >> BSHIFT;
        int pos = atomicAdd(&lh[b], 1);          // bucket-global slot
        if (pos < cap) {
            packed[(size_t)b * cap + pos] = (unsigned)s | ((unsigned)(d & (NPB - 1)) << 17);
        } else {
            int o = atomicAdd(ovf_cnt, 1);
            if (o < O_CAP) { ovf_dst[o] = d; ovf_src[o] = s; }
        }
    }
}

// ---------- D3: per-bucket scatter-max in LDS (proven body: lane=feature, 0 conflicts) ----------
__global__ void __launch_bounds__(BM_BLOCK)
bucket_max_kernel(const float* __restrict__ h,
                  const int* __restrict__ cnt, const int* __restrict__ ovf_cnt,
                  const int* __restrict__ ovf_dst, const int* __restrict__ ovf_src,
                  const int* __restrict__ src, const int* __restrict__ dst,
                  const unsigned* __restrict__ packed,
                  float* __restrict__ out, int N, int E, int cap) {
    __shared__ unsigned buf[NPB * D_FEAT];   // 16 KB
    int b = blockIdx.x;
    int tid = threadIdx.x;
    int node0 = b << BSHIFT;
    int nvals = (min(NPB, N - node0)) * D_FEAT;

    for (int i = tid; i < NPB * D_FEAT; i += BM_BLOCK) buf[i] = ENC_NEG_INF;
    __syncthreads();

    int total = cnt[b];
    int beg = b * cap;
    int end = beg + min(total, cap);
    int wid = tid >> 6;
    int lane = tid & 63;

    for (int base = beg + (wid << 6); base < end; base += BM_BLOCK) {
        int nk = min(64, end - base);
        unsigned p = (lane < nk) ? packed[base + lane] : 0u;
        int j = 0;
        for (; j + 8 <= nk; j += 8) {
            unsigned q[8];
            float v[8];
            #pragma unroll
            for (int k = 0; k < 8; ++k) q[k] = (unsigned)__shfl((int)p, j + k);
            #pragma unroll
            for (int k = 0; k < 8; ++k) v[k] = h[(size_t)(q[k] & 0x1FFFFu) * D_FEAT + lane];
            #pragma unroll
            for (int k = 0; k < 8; ++k)
                atomicMax(&buf[(q[k] >> 17) * D_FEAT + lane], enc_f32(v[k]));
        }
        for (; j < nk; ++j) {
            unsigned pj = (unsigned)__shfl((int)p, j);
            float v = h[(size_t)(pj & 0x1FFFFu) * D_FEAT + lane];
            atomicMax(&buf[(pj >> 17) * D_FEAT + lane], enc_f32(v));
        }
    }

    // ---- overflow safety net (ov == 0 on sane data: one broadcast load + branch) ----
    int ov = *ovf_cnt;
    if (ov > 0) {
        if (ov <= O_CAP) {
            for (int i = 0; i < ov; ++i) {           // list entries broadcast to all lanes
                int d = ovf_dst[i];
                if ((d >> BSHIFT) == b) {
                    float v = h[(size_t)ovf_src[i] * D_FEAT + lane];
                    atomicMax(&buf[(d & (NPB - 1)) * D_FEAT + lane], enc_f32(v));
                }
            }
        } else if (total > cap) {
            // truncated list: rescan all edges for this bucket (max is idempotent)
            for (int e = tid; e < E; e += BM_BLOCK) {
                int d = dst[e];
                if ((d >> BSHIFT) == b) {
                    const float* hr = h + (size_t)src[e] * D_FEAT;
                    int row = (d & (NPB - 1)) * D_FEAT;
                    for (int f = 0; f < D_FEAT; ++f)
                        atomicMax(&buf[row + f], enc_f32(hr[f]));
                }
            }
        }
    }
    __syncthreads();

    if (nvals == NPB * D_FEAT) {
        uint4* o4 = (uint4*)(out + (size_t)node0 * D_FEAT);
        const uint4* b4 = (const uint4*)buf;
        for (int i = tid; i < (NPB * D_FEAT) / 4; i += BM_BLOCK) {
            uint4 u = b4[i];
            uint4 r;
            r.x = dec_bits(u.x); r.y = dec_bits(u.y);
            r.z = dec_bits(u.z); r.w = dec_bits(u.w);
            o4[i] = r;
        }
    } else {
        unsigned* o = (unsigned*)(out + (size_t)node0 * D_FEAT);
        for (int i = tid; i < nvals; i += BM_BLOCK) o[i] = dec_bits(buf[i]);
    }
}

// ---------- fallback: atomic scatter (large-N / tiny-ws path) ----------
__global__ void init_out_kernel(uint4* __restrict__ out, int n4) {
    int i = blockIdx.x * blockDim.x + threadIdx.x;
    if (i < n4) {
        uint4 v;
        v.x = NEG_INF_BITS; v.y = NEG_INF_BITS; v.z = NEG_INF_BITS; v.w = NEG_INF_BITS;
        out[i] = v;
    }
}
__global__ void scatter_max_kernel(const float* __restrict__ h, const int* __restrict__ src,
                                   const int* __restrict__ dst, float* __restrict__ out, int E) {
    int gid = blockIdx.x * blockDim.x + threadIdx.x;
    int e = gid >> 6;
    if (e >= E) return;
    int lane = gid & 63;
    float v = h[src[e] * D_FEAT + lane];
    int* addr = (int*)(out + dst[e] * D_FEAT + lane);
    if (v >= 0.0f) atomicMax(addr, __float_as_int(v));
    else           atomicMin((unsigned int*)addr, __float_as_uint(v));
}
__global__ void finalize_kernel(float* __restrict__ out, int n) {
    int i = blockIdx.x * blockDim.x + threadIdx.x;
    if (i < n && __float_as_uint(out[i]) == NEG_INF_BITS) out[i] = 0.0f;
}

// ---------- launch ----------
extern "C" void kernel_launch(void* const* d_in, const int* in_sizes, int n_in,
                              void* d_out, int out_size, void* d_ws, size_t ws_size,
                              hipStream_t stream) {
    const float* h = (const float*)d_in[0];
    const int* edge_index = (const int*)d_in[1];
    int E = in_sizes[1] / 2;                 // edge_index is [2, E] row-major
    const int* src = edge_index;
    const int* dst = edge_index + E;
    float* out = (float*)d_out;
    int N = out_size / D_FEAT;

    int B = (N + NPB - 1) >> BSHIFT;

    // fixed per-bucket capacity: 1.25x mean degree, 64-aligned, floor 128
    int cap = 0;
    if (B > 0) {
        cap = (((E / B) * 5) / 4 + 63) & ~63;
        if (cap < 128) cap = 128;
    }
    size_t need = ((size_t)B + 1 + 2 * (size_t)O_CAP + (size_t)B * cap) * sizeof(int);

    if (N <= (1 << 17) && B <= MAXB && E > 0 && cap > 0 && ws_size >= need) {
        int* cnt         = (int*)d_ws;                   // [B]
        int* ovf_cnt     = cnt + B;                      // [1]
        int* ovf_dst     = ovf_cnt + 1;                  // [O_CAP]
        int* ovf_src     = ovf_dst + O_CAP;              // [O_CAP]
        unsigned* packed = (unsigned*)(ovf_src + O_CAP); // [B*cap]

        int aligned4 = (((((uintptr_t)dst) | ((uintptr_t)src)) & 15) == 0) ? 1 : 0;

        hipMemsetAsync(cnt, 0, (size_t)(B + 1) * sizeof(int), stream);

        int Te = ((E + PL_BLOCKS - 1) / PL_BLOCKS + 3) & ~3;   // chunk, multiple of 4
        place_kernel<<<PL_BLOCKS, PL_THREADS, 0, stream>>>(
            src, dst, cnt, ovf_cnt, ovf_dst, ovf_src, packed, E, Te, B, cap, aligned4);

        bucket_max_kernel<<<B, BM_BLOCK, 0, stream>>>(
            h, cnt, ovf_cnt, ovf_dst, ovf_src, src, dst, packed, out, N, E, cap);
    } else {
        int n4 = out_size / 4;
        init_out_kernel<<<(n4 + 255) / 256, 256, 0, stream>>>((uint4*)out, n4);
        long long total = (long long)E * 64;
        scatter_max_kernel<<<(int)((total + 255) / 256), 256, 0, stream>>>(h, src, dst, out, E);
        finalize_kernel<<<(out_size + 255) / 256, 256, 0, stream>>>(out, out_size);
    }
}